// Round 4
// baseline (803.746 us; speedup 1.0000x reference)
//
#include <hip/hip_runtime.h>

#define VOCAB 40
#define SEQ 128
#define THREADS 256
#define ROWS_PER_BLOCK (THREADS / 2)  // 2 threads per row
#define PASSES 3                      // DIAGNOSTIC: 3 accumulating passes
#define HW 21  // 20 hist words (40 bins, 16-bit packed) + 1 pad; gcd(21,32)=1

// DIAGNOSTIC ROUND: counts accumulate across PASSES without re-zero, so every
// pass's work is live (no DCE). All 6 features are scale-invariant in the
// counts (ratios, argmax, presence), so 3x counts give bit-identical features.
// 16-bit packing: max per-bin 3*128*2(pair merge) = 768 < 65536.

__global__ __launch_bounds__(THREADS) void char_dist_kernel(
    const int* __restrict__ x, float* __restrict__ out, int batch) {
  __shared__ unsigned int hist[THREADS * HW];
  const int tid = threadIdx.x;
  const int row = blockIdx.x * ROWS_PER_BLOCK + (tid >> 1);
  const int half = tid & 1;
  const bool active = row < batch;

  unsigned int* h = &hist[tid * HW];
#pragma unroll
  for (int w = 0; w < 20; ++w) h[w] = 0u;

  if (active) {
    const int4* rowp = reinterpret_cast<const int4*>(x) +
                       ((long)row * (SEQ / 4) + half * (SEQ / 8));
    for (int p = 0; p < PASSES; ++p) {
      // Opaque pointer: compiler cannot CSE/hoist loads across passes.
      asm volatile("" : "+v"(rowp));
#pragma unroll
      for (int j = 0; j < 16; ++j) {
        int4 t = rowp[j];
        h[t.x >> 1] += 1u << ((t.x & 1) << 4);
        h[t.y >> 1] += 1u << ((t.y & 1) << 4);
        h[t.z >> 1] += 1u << ((t.z & 1) << 4);
        h[t.w >> 1] += 1u << ((t.w & 1) << 4);
      }
    }
  }
  __syncthreads();

  // Merge pair partials (u32 add is safe: 16-bit lanes can't overflow).
  // Even thread: words 0..9 (bins 0..19); odd: words 10..19 (bins 20..39).
  const unsigned int* hp = &hist[(tid ^ 1) * HW];
  int total = 0, uniq = 0, maxc = 0, minc = 0x7fffffff;
  int letters = 0, digits = 0, special = 0;
  const int wbase = half * 10;
#pragma unroll
  for (int k = 0; k < 10; ++k) {
    const int w = wbase + k;
    const unsigned int m = h[w] + hp[w];
#pragma unroll
    for (int b = 0; b < 2; ++b) {
      const int bin = w * 2 + b;
      const int c = (int)((m >> (b * 16)) & 0xFFFFu);
      if (bin != 0) {  // bin 0 is padding, excluded from all stats
        total += c;
        uniq += (c > 0) ? 1 : 0;
        maxc = max(maxc, c);
        if (c > 0) minc = min(minc, c);
        if (bin <= 26) letters += c;
        else if (bin <= 36) digits += c;
        else special += c;
      }
    }
  }

  // Combine the two half-row partials within the lane pair.
  total   += __shfl_xor(total, 1);
  uniq    += __shfl_xor(uniq, 1);
  letters += __shfl_xor(letters, 1);
  digits  += __shfl_xor(digits, 1);
  special += __shfl_xor(special, 1);
  maxc = max(maxc, __shfl_xor(maxc, 1));
  minc = min(minc, __shfl_xor(minc, 1));

  if (active) {
    if (minc == 0x7fffffff) minc = 0;  // empty row
    // Counts are PASSES*true, but every feature is a ratio of counts (or a
    // presence count), so the scale cancels exactly.
    const float inv = 1.0f / (float)max(total, 1);
    const float f0 = (float)uniq * (1.0f / (float)VOCAB);
    const float f1 = (float)maxc * inv;
    const float f2 = (float)minc * inv;
    const float f3 = (float)letters * inv;
    const float f4 = (float)digits * inv;
    const float f5 = (float)special * inv;
    float2* o = reinterpret_cast<float2*>(out + (long)row * 6);
    if (half == 0) {
      o[0] = make_float2(f0, f1);
      o[1] = make_float2(f2, f3);
    } else {
      o[2] = make_float2(f4, f5);
    }
  }
}

extern "C" void kernel_launch(void* const* d_in, const int* in_sizes, int n_in,
                              void* d_out, int out_size, void* d_ws, size_t ws_size,
                              hipStream_t stream) {
  const int* x = (const int*)d_in[0];
  float* out = (float*)d_out;
  const int batch = in_sizes[0] / SEQ;
  const int blocks = (batch + ROWS_PER_BLOCK - 1) / ROWS_PER_BLOCK;
  char_dist_kernel<<<blocks, THREADS, 0, stream>>>(x, out, batch);
}

// Round 5
// 192.146 us; speedup vs baseline: 4.1830x; 4.1830x over previous
//
#include <hip/hip_runtime.h>

#define VOCAB 40
#define SEQ 128
#define THREADS 256          // 1 thread = 1 row; block = 256 rows
#define RSTRIDE 36           // LDS row stride in words: 32 tokens + 4 pad
                             // -> bank group 4*((r+k)%8): even tiling, conflict-free
#define HW 11                // 10 byte-packed hist words + 1 pad (gcd(11,32)=1)

__global__ __launch_bounds__(THREADS) void char_dist_kernel(
    const int* __restrict__ x, float* __restrict__ out, int batch) {
  __shared__ unsigned int tile[THREADS * RSTRIDE];   // 36864 B
  __shared__ unsigned int hist[THREADS * HW];        // 11264 B
  const int tid = threadIdx.x;
  const int rowBase = blockIdx.x * THREADS;

  unsigned int* h = &hist[tid * HW];
#pragma unroll
  for (int w = 0; w < 10; ++w) h[w] = 0u;

  // ---- staging geometry ----
  // chunk c (0..3) covers tokens [32c, 32c+32) of all 256 rows.
  // instr k (0..7): thread i handles row k*32 + (i>>3), 16B-block (i&7).
  // Global: 8-lane groups read 128 B contiguous -> full-line consumption.
  const int lrow = tid >> 3;           // 0..31
  const int lblk = tid & 7;            // 0..7
  const int4* gbase = reinterpret_cast<const int4*>(x);

#define LOAD_CHUNK(R, c)                                                     \
  _Pragma("unroll") for (int k = 0; k < 8; ++k) {                            \
    const int r = k * 32 + lrow;                                             \
    const long grow = (long)(rowBase + r);                                   \
    (R)[k] = (grow < batch) ? gbase[grow * 32 + (c) * 8 + lblk]              \
                            : make_int4(0, 0, 0, 0);                         \
  }

#define STORE_CHUNK(R)                                                       \
  _Pragma("unroll") for (int k = 0; k < 8; ++k) {                            \
    const int r = k * 32 + lrow;                                             \
    *reinterpret_cast<int4*>(&tile[r * RSTRIDE + lblk * 4]) = (R)[k];        \
  }

#define PROC_CHUNK()                                                         \
  _Pragma("unroll") for (int k = 0; k < 8; ++k) {                            \
    const int4 t4 =                                                          \
        *reinterpret_cast<const int4*>(&tile[tid * RSTRIDE + k * 4]);        \
    h[t4.x >> 2] += 1u << ((t4.x & 3) << 3);                                 \
    h[t4.y >> 2] += 1u << ((t4.y & 3) << 3);                                 \
    h[t4.z >> 2] += 1u << ((t4.z & 3) << 3);                                 \
    h[t4.w >> 2] += 1u << ((t4.w & 3) << 3);                                 \
  }

  int4 A[8], B[8];
  LOAD_CHUNK(A, 0)
  // c = 0
  LOAD_CHUNK(B, 1)
  STORE_CHUNK(A)
  __syncthreads();
  PROC_CHUNK()
  __syncthreads();
  // c = 1
  LOAD_CHUNK(A, 2)
  STORE_CHUNK(B)
  __syncthreads();
  PROC_CHUNK()
  __syncthreads();
  // c = 2
  LOAD_CHUNK(B, 3)
  STORE_CHUNK(A)
  __syncthreads();
  PROC_CHUNK()
  __syncthreads();
  // c = 3
  STORE_CHUNK(B)
  __syncthreads();
  PROC_CHUNK()

  // ---- epilogue: unpack own 40-bin byte-packed histogram ----
  const int row = rowBase + tid;
  if (row >= batch) return;

  int total = 0, uniq = 0, maxc = 0, minc = 0x7fffffff;
  int letters = 0, digits = 0, special = 0;
#pragma unroll
  for (int w = 0; w < 10; ++w) {
    const unsigned int m = h[w];
#pragma unroll
    for (int b = 0; b < 4; ++b) {
      const int bin = w * 4 + b;
      const int c = (int)((m >> (b * 8)) & 0xFFu);
      if (bin != 0) {  // bin 0 is padding, excluded from all stats
        total += c;
        uniq += (c > 0) ? 1 : 0;
        maxc = max(maxc, c);
        if (c > 0) minc = min(minc, c);
        if (bin <= 26) letters += c;
        else if (bin <= 36) digits += c;
        else special += c;
      }
    }
  }

  float f0, f1, f2, f3, f4, f5;
  if (total > 0) {
    const float inv = 1.0f / (float)total;
    f0 = (float)uniq * (1.0f / (float)VOCAB);
    f1 = (float)maxc * inv;
    f2 = (float)minc * inv;
    f3 = (float)letters * inv;
    f4 = (float)digits * inv;
    f5 = (float)special * inv;
  } else {
    f0 = f1 = f2 = f3 = f4 = f5 = 0.0f;
  }
  float2* o = reinterpret_cast<float2*>(out + (long)row * 6);
  o[0] = make_float2(f0, f1);
  o[1] = make_float2(f2, f3);
  o[2] = make_float2(f4, f5);
}

extern "C" void kernel_launch(void* const* d_in, const int* in_sizes, int n_in,
                              void* d_out, int out_size, void* d_ws, size_t ws_size,
                              hipStream_t stream) {
  const int* x = (const int*)d_in[0];
  float* out = (float*)d_out;
  const int batch = in_sizes[0] / SEQ;
  const int blocks = (batch + THREADS - 1) / THREADS;
  char_dist_kernel<<<blocks, THREADS, 0, stream>>>(x, out, batch);
}